// Round 1
// baseline (795.664 us; speedup 1.0000x reference)
//
#include <hip/hip_runtime.h>

// HBVMulTDET: 365-step HBV scan over [Ngrid=2000 x NMUL=16] chains + NMUL-mean
// + 15-tap gamma-UH routing conv, fused in one kernel.
// Layout: block=64 threads = 4 grids x 16 muls; thread = (grid gl, mul m).
// NMUL-mean via DPP row_ror butterfly (16-lane rows == mul groups).

#define LENF 15

__device__ __forceinline__ float flog2(float x) { return __builtin_amdgcn_logf(x); }
__device__ __forceinline__ float fexp2(float x) { return __builtin_amdgcn_exp2f(x); }
__device__ __forceinline__ float fpow(float x, float y) { return fexp2(y * flog2(x)); }

template <int CTRL>
__device__ __forceinline__ float dpp_add(float x) {
    int p = __builtin_amdgcn_update_dpp(0, __float_as_int(x), CTRL, 0xF, 0xF, true);
    return x + __int_as_float(p);
}

__global__ __launch_bounds__(64) void hbv_kernel(
    const float* __restrict__ x,        // [Nstep, Ngrid, 3]
    const float* __restrict__ praw,     // [Nstep, Ngrid, 14, 16]
    const float* __restrict__ convp,    // [Ngrid, 2]
    float* __restrict__ out,            // [Nstep, Ngrid]
    int Nstep, int Ngrid)
{
    const int tid = threadIdx.x;
    const int gl  = tid >> 4;     // grid within block: 0..3
    const int m   = tid & 15;     // mul component: 0..15
    const int g0  = blockIdx.x * 4;
    const int g   = g0 + gl;

    // ---- stage forcings for this block's 4 grids into LDS: lds[t*12 + gl*3 + c]
    __shared__ float4 lds4[1104];           // 365*3=1095 float4 rows + pad
    float* ldsx = (float*)lds4;
    {
        const float4* src = (const float4*)(x + (size_t)g0 * 3); // g0 % 4 == 0 -> 16B aligned
        const int row4   = (Ngrid * 3) >> 2;                     // float4s per t-row (1500)
        const int total4 = Nstep * 3;                            // 1095
        float4 tmp[18];
        #pragma unroll
        for (int k = 0; k < 18; ++k) {
            int j = tid + (k << 6);
            if (j < total4) {
                int t = j / 3, q = j - t * 3;
                tmp[k] = src[(size_t)t * row4 + q];
            }
        }
        #pragma unroll
        for (int k = 0; k < 18; ++k) {
            int j = tid + (k << 6);
            if (j < total4) lds4[j] = tmp[k];
        }
    }
    __syncthreads();

    // ---- static params: praw[Nstep-1, g, i, m] scaled to bounds
    const float lo[14] = {1.0f, 50.0f, 0.05f, 0.01f, 0.001f, 0.2f, 0.0f, 0.0f,
                          -2.5f, 0.5f, 0.0f, 0.0f, 0.3f, 0.0f};
    const float hi[14] = {6.0f, 1000.0f, 0.9f, 0.5f, 0.2f, 1.0f, 10.0f, 100.0f,
                          2.5f, 10.0f, 0.1f, 0.2f, 5.0f, 1.0f};
    float par[14];
    {
        const float* pr = praw + ((size_t)(Nstep - 1) * Ngrid + g) * 14 * 16 + m;
        #pragma unroll
        for (int i = 0; i < 14; ++i)
            par[i] = fmaf(pr[i * 16], hi[i] - lo[i], lo[i]);
    }
    const float pBETA = par[0], pFC = par[1], pK0 = par[2], pK1 = par[3], pK2 = par[4],
                pLP = par[5], pPERC = par[6], pUZL = par[7], pTT = par[8], pCFMAX = par[9],
                pCFR = par[10], pCWH = par[11], pBETAET = par[12], pC = par[13];
    const float invFC    = 1.0f / pFC;
    const float invLPFC  = 1.0f / (pLP * pFC);
    const float cfrcfmax = pCFR * pCFMAX;

    // ---- gamma unit hydrograph (denominator cancels under normalization)
    float uh[LENF];
    {
        float a  = convp[g * 2 + 0] * 2.9f;
        float bb = convp[g * 2 + 1] * 6.5f;
        float aa = fmaxf(a, 0.0f) + 0.1f;
        float th = fmaxf(bb, 0.0f) + 0.5f;
        float am1 = aa - 1.0f;
        float c1  = 1.4426950408889634f / th;  // log2(e)/theta
        const float L[LENF] = {  // log2(k + 0.5)
            -1.0f, 0.5849625007f, 1.3219280949f, 1.8073549221f, 2.1699250014f,
            2.4594316186f, 2.7004397181f, 2.9068905956f, 3.0874628413f, 3.2479275134f,
            3.3923174228f, 3.5235619561f, 3.6438561898f, 3.7548875022f, 3.8579809951f};
        float s = 0.0f;
        #pragma unroll
        for (int k = 0; k < LENF; ++k) {
            float t = (float)k + 0.5f;
            float w = fexp2(fmaf(am1, L[k], -t * c1));  // t^(aa-1) * exp(-t/theta)
            uh[k] = w;
            s += w;
        }
        float is = 1.0f / s;
        #pragma unroll
        for (int k = 0; k < LENF; ++k) uh[k] *= is;
    }

    // ---- scan
    const float NZ = 1e-5f;
    float SNOWPACK = 1e-3f, MELTWATER = 1e-3f, SM = 1e-3f, SUZ = 1e-3f, SLZ = 1e-3f;
    float h[LENF];
    #pragma unroll
    for (int k = 0; k < LENF; ++k) h[k] = 0.0f;

    int b = gl * 3;
    float Pc = ldsx[b], Tc = ldsx[b + 1], Ec = ldsx[b + 2];
    float* orow = out + g;

    for (int t = 0; t < Nstep; ++t) {
        b += 12;
        float Pn = ldsx[b], Tn = ldsx[b + 1], En = ldsx[b + 2];  // prefetch next step

        float P = Pc, T = Tc, PET = Ec;
        bool warm  = (T >= pTT);
        float RAIN = warm ? P : 0.0f;
        float SNOW = warm ? 0.0f : P;
        SNOWPACK += SNOW;
        float melt = fminf(fmaxf(pCFMAX * (T - pTT), 0.0f), SNOWPACK);
        MELTWATER += melt;
        SNOWPACK = fmaxf(SNOWPACK - melt, NZ);
        float refr = fminf(fmaxf(cfrcfmax * (pTT - T), 0.0f), MELTWATER);
        SNOWPACK += refr;
        MELTWATER = fmaxf(MELTWATER - refr, NZ);
        float tosoil = fmaxf(fmaf(-pCWH, SNOWPACK, MELTWATER), 0.0f);
        MELTWATER = fmaxf(MELTWATER - tosoil, NZ);
        float sw = fminf(fpow(SM * invFC, pBETA), 1.0f);
        float rt = RAIN + tosoil;
        float recharge = rt * sw;
        SM = SM + rt - recharge;
        float excess = fmaxf(SM - pFC, 0.0f);
        SM = fmaxf(SM - excess, NZ);
        float ev = fminf(fpow(SM * invLPFC, pBETAET), 1.0f);
        float ETact = fminf(SM, PET * ev);
        SM = fmaxf(SM - ETact, NZ);
        float cap = fminf(SLZ, pC * SLZ * (1.0f - fminf(SM * invFC, 1.0f)));
        SM  = fmaxf(SM + cap, NZ);
        SLZ = fmaxf(SLZ - cap, NZ);
        SUZ = SUZ + recharge + excess;
        float perc = fminf(SUZ, pPERC);
        SUZ -= perc;
        float Q0 = pK0 * fmaxf(SUZ - pUZL, 0.0f);
        SUZ -= Q0;
        float Q1 = pK1 * SUZ;
        SUZ -= Q1;
        SLZ += perc;
        float Q2 = pK2 * SLZ;
        SLZ -= Q2;
        float q = Q0 + Q1 + Q2;

        // mean over the 16 mul components (16-lane DPP row butterfly)
        float qs = q;
        qs = dpp_add<0x121>(qs);  // row_ror:1
        qs = dpp_add<0x122>(qs);  // row_ror:2
        qs = dpp_add<0x124>(qs);  // row_ror:4
        qs = dpp_add<0x128>(qs);  // row_ror:8
        float qavg = qs * 0.0625f;

        // fused causal 15-tap routing conv (shift-register history)
        #pragma unroll
        for (int k = LENF - 1; k > 0; --k) h[k] = h[k - 1];
        h[0] = qavg;
        float r0 = 0.0f, r1 = 0.0f, r2 = 0.0f;
        #pragma unroll
        for (int k = 0; k + 2 < LENF; k += 3) {
            r0 = fmaf(uh[k], h[k], r0);
            r1 = fmaf(uh[k + 1], h[k + 1], r1);
            r2 = fmaf(uh[k + 2], h[k + 2], r2);
        }
        if (m == 0) orow[(size_t)t * Ngrid] = r0 + r1 + r2;

        Pc = Pn; Tc = Tn; Ec = En;
    }
}

extern "C" void kernel_launch(void* const* d_in, const int* in_sizes, int n_in,
                              void* d_out, int out_size, void* d_ws, size_t ws_size,
                              hipStream_t stream) {
    const float* x     = (const float*)d_in[0];
    // d_in[1] = c_hydro_model — unused by the reference
    const float* praw  = (const float*)d_in[2];
    const float* convp = (const float*)d_in[3];
    float* out = (float*)d_out;

    int Ngrid = in_sizes[3] / 2;                 // conv_params_hydro: [Ngrid, 2]
    int Nstep = in_sizes[0] / (3 * Ngrid);       // x: [Nstep, Ngrid, 3]
    int blocks = Ngrid / 4;                      // 4 grids per 64-thread block

    hbv_kernel<<<blocks, 64, 0, stream>>>(x, praw, convp, out, Nstep, Ngrid);
}

// Round 2
// 779.846 us; speedup vs baseline: 1.0203x; 1.0203x over previous
//
#include <hip/hip_runtime.h>

// HBVMulTDET: 365-step HBV scan over [Ngrid=2000 x NMUL=16] chains + NMUL-mean
// + 15-tap gamma-UH routing conv.
// R1: routing conv DEFERRED out of the serial scan. Scan stores qavg per step
// to LDS (DPP 16-lane mean + masked ds_write); a parallel post-phase does the
// 15-tap conv + global stores. Scan body shrinks ~110 -> ~80 instrs.
// Layout: block=64 threads = 4 grids x 16 muls; thread = (grid gl, mul m).

#define LENF 15

__device__ __forceinline__ float flog2(float x) { return __builtin_amdgcn_logf(x); }
__device__ __forceinline__ float fexp2(float x) { return __builtin_amdgcn_exp2f(x); }
__device__ __forceinline__ float fpow(float x, float y) { return fexp2(y * flog2(x)); }

template <int CTRL>
__device__ __forceinline__ float dpp_add(float x) {
    int p = __builtin_amdgcn_update_dpp(0, __float_as_int(x), CTRL, 0xF, 0xF, true);
    return x + __int_as_float(p);
}

__global__ __launch_bounds__(64, 1) void hbv_kernel(
    const float* __restrict__ x,        // [Nstep, Ngrid, 3]
    const float* __restrict__ praw,     // [Nstep, Ngrid, 14, 16]
    const float* __restrict__ convp,    // [Ngrid, 2]
    float* __restrict__ out,            // [Nstep, Ngrid]
    int Nstep, int Ngrid)
{
    const int tid = threadIdx.x;
    const int gl  = tid >> 4;     // grid within block: 0..3
    const int m   = tid & 15;     // mul component: 0..15
    const int g0  = blockIdx.x * 4;
    const int g   = g0 + gl;

    // ---- LDS: forcings [t][gl][3] (stride 12 floats) + qavg [t][gl]
    __shared__ float4 lds4[1104];           // 365*3=1095 float4 rows + pad
    __shared__ float  qbuf[366 * 4];        // qavg[t*4+gl]
    float* ldsx = (float*)lds4;

    {   // stage forcings for this block's 4 grids (one-time)
        const float4* src = (const float4*)(x + (size_t)g0 * 3); // g0%4==0 -> 16B aligned
        const int row4   = (Ngrid * 3) >> 2;                     // float4s per t-row
        const int total4 = Nstep * 3;                            // 1095
        float4 tmp[18];
        #pragma unroll
        for (int k = 0; k < 18; ++k) {
            int j = tid + (k << 6);
            if (j < total4) {
                int t = j / 3, q = j - t * 3;
                tmp[k] = src[(size_t)t * row4 + q];
            }
        }
        #pragma unroll
        for (int k = 0; k < 18; ++k) {
            int j = tid + (k << 6);
            if (j < total4) lds4[j] = tmp[k];
        }
    }
    __syncthreads();

    // ---- static params: praw[Nstep-1, g, i, m] scaled to bounds
    const float lo[14] = {1.0f, 50.0f, 0.05f, 0.01f, 0.001f, 0.2f, 0.0f, 0.0f,
                          -2.5f, 0.5f, 0.0f, 0.0f, 0.3f, 0.0f};
    const float hi[14] = {6.0f, 1000.0f, 0.9f, 0.5f, 0.2f, 1.0f, 10.0f, 100.0f,
                          2.5f, 10.0f, 0.1f, 0.2f, 5.0f, 1.0f};
    float par[14];
    {
        const float* pr = praw + ((size_t)(Nstep - 1) * Ngrid + g) * 14 * 16 + m;
        #pragma unroll
        for (int i = 0; i < 14; ++i)
            par[i] = fmaf(pr[i * 16], hi[i] - lo[i], lo[i]);
    }
    const float pBETA = par[0], pFC = par[1], pK0 = par[2], pK1 = par[3], pK2 = par[4],
                pLP = par[5], pPERC = par[6], pUZL = par[7], pTT = par[8], pCFMAX = par[9],
                pCFR = par[10], pCWH = par[11], pBETAET = par[12], pC = par[13];
    const float invFC    = 1.0f / pFC;
    const float invLPFC  = 1.0f / (pLP * pFC);
    const float cfrcfmax = pCFR * pCFMAX;

    // ---- gamma unit hydrograph (denominator cancels under normalization)
    float uh[LENF];
    {
        float a  = convp[g * 2 + 0] * 2.9f;
        float bb = convp[g * 2 + 1] * 6.5f;
        float aa = fmaxf(a, 0.0f) + 0.1f;
        float th = fmaxf(bb, 0.0f) + 0.5f;
        float am1 = aa - 1.0f;
        float c1  = 1.4426950408889634f / th;  // log2(e)/theta
        const float L[LENF] = {  // log2(k + 0.5)
            -1.0f, 0.5849625007f, 1.3219280949f, 1.8073549221f, 2.1699250014f,
            2.4594316186f, 2.7004397181f, 2.9068905956f, 3.0874628413f, 3.2479275134f,
            3.3923174228f, 3.5235619561f, 3.6438561898f, 3.7548875022f, 3.8579809951f};
        float s = 0.0f;
        #pragma unroll
        for (int k = 0; k < LENF; ++k) {
            float t = (float)k + 0.5f;
            float w = fexp2(fmaf(am1, L[k], -t * c1));  // t^(aa-1) * exp(-t/theta)
            uh[k] = w;
            s += w;
        }
        float is = 1.0f / s;
        #pragma unroll
        for (int k = 0; k < LENF; ++k) uh[k] *= is;
    }

    // ---- serial scan (lean body: state update + DPP mean + LDS write)
    const float NZ = 1e-5f;
    float SNOWPACK = 1e-3f, MELTWATER = 1e-3f, SM = 1e-3f, SUZ = 1e-3f, SLZ = 1e-3f;

    int b = gl * 3;
    float Pc = ldsx[b], Tc = ldsx[b + 1], Ec = ldsx[b + 2];
    float* qrow = qbuf + gl;

    for (int t = 0; t < Nstep; ++t) {
        b += 12;
        float Pn = ldsx[b], Tn = ldsx[b + 1], En = ldsx[b + 2];  // prefetch next step

        float P = Pc, T = Tc, PET = Ec;
        bool warm  = (T >= pTT);
        float RAIN = warm ? P : 0.0f;
        float SNOW = warm ? 0.0f : P;
        SNOWPACK += SNOW;
        float melt = fminf(fmaxf(pCFMAX * (T - pTT), 0.0f), SNOWPACK);
        MELTWATER += melt;
        SNOWPACK = fmaxf(SNOWPACK - melt, NZ);
        float refr = fminf(fmaxf(cfrcfmax * (pTT - T), 0.0f), MELTWATER);
        SNOWPACK += refr;
        MELTWATER = fmaxf(MELTWATER - refr, NZ);
        float tosoil = fmaxf(fmaf(-pCWH, SNOWPACK, MELTWATER), 0.0f);
        MELTWATER = fmaxf(MELTWATER - tosoil, NZ);
        float sw = fminf(fpow(SM * invFC, pBETA), 1.0f);
        float rt = RAIN + tosoil;
        float recharge = rt * sw;
        SM = SM + rt - recharge;
        float excess = fmaxf(SM - pFC, 0.0f);
        SM = fmaxf(SM - excess, NZ);
        float ev = fminf(fpow(SM * invLPFC, pBETAET), 1.0f);
        float ETact = fminf(SM, PET * ev);
        SM = fmaxf(SM - ETact, NZ);
        float cap = fminf(SLZ, pC * SLZ * (1.0f - fminf(SM * invFC, 1.0f)));
        SM  = fmaxf(SM + cap, NZ);
        SLZ = fmaxf(SLZ - cap, NZ);
        SUZ = SUZ + recharge + excess;
        float perc = fminf(SUZ, pPERC);
        SUZ -= perc;
        float Q0 = pK0 * fmaxf(SUZ - pUZL, 0.0f);
        SUZ -= Q0;
        float Q1 = pK1 * SUZ;
        SUZ -= Q1;
        SLZ += perc;
        float Q2 = pK2 * SLZ;
        SLZ -= Q2;
        float q = Q0 + Q1 + Q2;

        // mean over the 16 mul components (16-lane DPP row butterfly)
        float qs = q;
        qs = dpp_add<0x121>(qs);  // row_ror:1
        qs = dpp_add<0x122>(qs);  // row_ror:2
        qs = dpp_add<0x124>(qs);  // row_ror:4
        qs = dpp_add<0x128>(qs);  // row_ror:8
        if (m == 0) qrow[t * 4] = qs * 0.0625f;

        Pc = Pn; Tc = Tn; Ec = En;
    }
    __syncthreads();

    // ---- parallel routing conv: lane m covers a contiguous t-chunk of its grid
    const int chunk = (Nstep + 15) >> 4;          // 23 for Nstep=365
    int t0 = m * chunk;
    int t1 = min(t0 + chunk, Nstep);
    float w[LENF];
    #pragma unroll
    for (int k = 0; k < LENF; ++k) {
        int tt = t0 - k;
        w[k] = (tt >= 0) ? qrow[tt * 4] : 0.0f;
    }
    for (int t = t0; t < t1; ++t) {
        float acc = 0.0f;
        #pragma unroll
        for (int k = 0; k < LENF; ++k) acc = fmaf(uh[k], w[k], acc);
        out[(size_t)t * Ngrid + g] = acc;
        #pragma unroll
        for (int k = LENF - 1; k > 0; --k) w[k] = w[k - 1];
        w[0] = (t + 1 < Nstep) ? qrow[(t + 1) * 4] : 0.0f;
    }
}

extern "C" void kernel_launch(void* const* d_in, const int* in_sizes, int n_in,
                              void* d_out, int out_size, void* d_ws, size_t ws_size,
                              hipStream_t stream) {
    const float* x     = (const float*)d_in[0];
    // d_in[1] = c_hydro_model — unused by the reference
    const float* praw  = (const float*)d_in[2];
    const float* convp = (const float*)d_in[3];
    float* out = (float*)d_out;

    int Ngrid = in_sizes[3] / 2;                 // conv_params_hydro: [Ngrid, 2]
    int Nstep = in_sizes[0] / (3 * Ngrid);       // x: [Nstep, Ngrid, 3]
    int blocks = Ngrid / 4;                      // 4 grids per 64-thread block

    hbv_kernel<<<blocks, 64, 0, stream>>>(x, praw, convp, out, Nstep, Ngrid);
}